// Round 4
// baseline (99.594 us; speedup 1.0000x reference)
//
#include <hip/hip_runtime.h>
#include <hip/hip_bf16.h>
#include <math.h>

#define NB     2048
#define NC     1000
#define DDIM   128
#define LDT    136      // LDS row stride in bf16 (+8 pad: fragment reads 2-way = free)
#define NPROTO 256      // 16x16 proto tile-blocks; dist = 16x32 = 512; grid = 768

typedef __attribute__((ext_vector_type(8))) short  short8;
typedef __attribute__((ext_vector_type(4))) float  floatx4;

__device__ __forceinline__ float bf2f(unsigned short b) {
    union { float f; unsigned int u; } v; v.u = ((unsigned int)b) << 16;
    return v.f;
}

// stage 64 rows x 128 k of fp32 -> bf16 LDS tile (RNE), coalesced float4 reads
__device__ __forceinline__ void stage_cvt(const float* __restrict__ src, int row0, int clampr,
                                          unsigned short* __restrict__ lds, int t) {
    #pragma unroll
    for (int i = 0; i < 8; ++i) {
        int c = (i * 256 + t) * 4;             // 0..8191
        int r = c >> 7, k = c & 127;
        int gr = row0 + r; if (gr > clampr) gr = clampr;
        float4 v = *(const float4*)(src + gr * DDIM + k);
        union { __hip_bfloat162 h; unsigned int u; } p0, p1;
        p0.h = __float22bfloat162_rn(make_float2(v.x, v.y));
        p1.h = __float22bfloat162_rn(make_float2(v.z, v.w));
        uint2 st; st.x = p0.u; st.y = p1.u;
        *(uint2*)(lds + r * LDT + k) = st;     // 8B aligned: LDT*2=272%8==0, k%4==0
    }
}

// per-row squared norms of the ROUNDED bf16 values; 4 lanes per row
__device__ __forceinline__ void norm64(const unsigned short* __restrict__ tile,
                                       float* __restrict__ nrm, int t) {
    int r = t >> 2, seg = t & 3;
    const unsigned short* p = tile + r * LDT + seg * 32;
    float q = 0.0f;
    #pragma unroll
    for (int j = 0; j < 4; ++j) {
        short8 v = *(const short8*)(p + j * 8);
        #pragma unroll
        for (int e = 0; e < 8; ++e) { float f = bf2f((unsigned short)v[e]); q = fmaf(f, f, q); }
    }
    q += __shfl_xor(q, 1);
    q += __shfl_xor(q, 2);
    if (seg == 0) nrm[r] = q;
}

// 64x64 block tile: 4 waves, each a 2x2 of 16x16x32 bf16 MFMA tiles
__device__ __forceinline__ void gemm64(const unsigned short* __restrict__ As,
                                       const unsigned short* __restrict__ Bs,
                                       int lane, int w, floatx4 acc[2][2]) {
    int wm = (w >> 1) * 32, wn = (w & 1) * 32;
    int lm = lane & 15, q = lane >> 4;
    #pragma unroll
    for (int ks = 0; ks < 4; ++ks) {
        int ko = ks * 32 + q * 8;
        short8 a0 = *(const short8*)(As + (wm + lm) * LDT + ko);
        short8 a1 = *(const short8*)(As + (wm + 16 + lm) * LDT + ko);
        short8 b0 = *(const short8*)(Bs + (wn + lm) * LDT + ko);
        short8 b1 = *(const short8*)(Bs + (wn + 16 + lm) * LDT + ko);
        acc[0][0] = __builtin_amdgcn_mfma_f32_16x16x32_bf16(a0, b0, acc[0][0], 0, 0, 0);
        acc[0][1] = __builtin_amdgcn_mfma_f32_16x16x32_bf16(a0, b1, acc[0][1], 0, 0, 0);
        acc[1][0] = __builtin_amdgcn_mfma_f32_16x16x32_bf16(a1, b0, acc[1][0], 0, 0, 0);
        acc[1][1] = __builtin_amdgcn_mfma_f32_16x16x32_bf16(a1, b1, acc[1][1], 0, 0, 0);
    }
}

// blocks [0, 256): proto tiles -> atomicAdd scalar + release counter
// blocks [256,768): dist tiles -> spin on counter, store proto - dist
__global__ __launch_bounds__(256, 3) void fused_kernel(const float* __restrict__ F,
                                                       const float* __restrict__ W,
                                                       float* __restrict__ ws,
                                                       float* __restrict__ out) {
    __shared__ __align__(16) unsigned short As[64 * LDT];
    __shared__ __align__(16) unsigned short Bs[64 * LDT];
    __shared__ float nA[64], nB[64], red[4], sproto;
    unsigned int* cnt = (unsigned int*)ws + 1;

    int bid = blockIdx.x;
    bool isProto = bid < NPROTO;
    int by, bx; const float* Asrc; int aClamp;
    if (isProto) { by = bid >> 4;            bx = bid & 15; Asrc = W; aClamp = NC - 1; }
    else         { int d = bid - NPROTO; by = d >> 4; bx = d & 15; Asrc = F; aClamp = NB - 1; }
    int row0 = by * 64, col0 = bx * 64;
    int t = threadIdx.x;

    stage_cvt(Asrc, row0, aClamp, As, t);
    stage_cvt(W,    col0, NC - 1, Bs, t);
    __syncthreads();

    norm64(As, nA, t);
    norm64(Bs, nB, t);

    int lane = t & 63, w = t >> 6;
    floatx4 acc[2][2] = {{{0,0,0,0},{0,0,0,0}},{{0,0,0,0},{0,0,0,0}}};
    gemm64(As, Bs, lane, w, acc);
    __syncthreads();                       // norms visible to all

    int wm = (w >> 1) * 32, wn = (w & 1) * 32;
    int lm = lane & 15, q = lane >> 4;

    if (isProto) {
        float local = 0.0f;
        #pragma unroll
        for (int ti = 0; ti < 2; ++ti)
            #pragma unroll
            for (int tj = 0; tj < 2; ++tj) {
                int lc2 = wn + tj * 16 + lm;
                int c2  = col0 + lc2;
                if (c2 < NC) {
                    float n2 = nB[lc2];
                    #pragma unroll
                    for (int r = 0; r < 4; ++r) {
                        int lc1 = wm + ti * 16 + q * 4 + r;
                        int c1  = row0 + lc1;
                        if (c1 < NC) {
                            float d2 = nA[lc1] + n2 - 2.0f * acc[ti][tj][r];
                            local += sqrtf(fmaxf(d2, 0.0f));
                        }
                    }
                }
            }
        #pragma unroll
        for (int off = 32; off > 0; off >>= 1) local += __shfl_down(local, off);
        if (lane == 0) red[w] = local;
        __syncthreads();
        if (t == 0) {
            atomicAdd(ws, red[0] + red[1] + red[2] + red[3]);   // device scope
            __hip_atomic_fetch_add(cnt, 1u, __ATOMIC_RELEASE, __HIP_MEMORY_SCOPE_AGENT);
        }
    } else {
        // distances first (hide proto latency), then spin, then store
        float s[2][2][4];
        #pragma unroll
        for (int ti = 0; ti < 2; ++ti)
            #pragma unroll
            for (int tj = 0; tj < 2; ++tj) {
                float n2 = nB[wn + tj * 16 + lm];
                #pragma unroll
                for (int r = 0; r < 4; ++r) {
                    float d2 = nA[wm + ti * 16 + q * 4 + r] + n2 - 2.0f * acc[ti][tj][r];
                    s[ti][tj][r] = sqrtf(fmaxf(d2, 0.0f));
                }
            }
        if (t == 0) {
            while (__hip_atomic_load(cnt, __ATOMIC_ACQUIRE, __HIP_MEMORY_SCOPE_AGENT) != NPROTO)
                __builtin_amdgcn_s_sleep(1);
            sproto = __hip_atomic_load(ws, __ATOMIC_RELAXED, __HIP_MEMORY_SCOPE_AGENT);
        }
        __syncthreads();
        float proto = sproto;
        #pragma unroll
        for (int ti = 0; ti < 2; ++ti)
            #pragma unroll
            for (int tj = 0; tj < 2; ++tj) {
                int cg = col0 + wn + tj * 16 + lm;
                if (cg < NC) {
                    #pragma unroll
                    for (int r = 0; r < 4; ++r) {
                        int mg = row0 + wm + ti * 16 + q * 4 + r;
                        out[mg * NC + cg] = proto - s[ti][tj][r];
                    }
                }
            }
    }
}

extern "C" void kernel_launch(void* const* d_in, const int* in_sizes, int n_in,
                              void* d_out, int out_size, void* d_ws, size_t ws_size,
                              hipStream_t stream) {
    const float* F  = (const float*)d_in[0];   // (2048,128)
    const float* Wm = (const float*)d_in[1];   // (1000,128)
    float* out = (float*)d_out;                // (2048,1000)
    float* ws  = (float*)d_ws;

    hipMemsetAsync(ws, 0, 8, stream);          // proto scalar + done counter
    fused_kernel<<<768, 256, 0, stream>>>(F, Wm, ws, out);
}

// Round 5
// 68.252 us; speedup vs baseline: 1.4592x; 1.4592x over previous
//
#include <hip/hip_runtime.h>
#include <hip/hip_bf16.h>
#include <math.h>

#define NB   2048
#define NC   1000
#define DDIM 128
#define LDT  136      // LDS row stride in bf16 (+8 pad)
#define NPB  256      // proto partial slots in ws (16x16 tile grid)

typedef __attribute__((ext_vector_type(8))) short  short8;
typedef __attribute__((ext_vector_type(4))) float  floatx4;

__device__ __forceinline__ float bf2f(unsigned short b) {
    union { float f; unsigned int u; } v; v.u = ((unsigned int)b) << 16;
    return v.f;
}

// stage 64 rows x 128 k of fp32 -> bf16 LDS tile (RNE), coalesced float4 reads
__device__ __forceinline__ void stage_cvt(const float* __restrict__ src, int row0, int clampr,
                                          unsigned short* __restrict__ lds, int t) {
    #pragma unroll
    for (int i = 0; i < 8; ++i) {
        int c = (i * 256 + t) * 4;             // 0..8191
        int r = c >> 7, k = c & 127;
        int gr = row0 + r; if (gr > clampr) gr = clampr;
        float4 v = *(const float4*)(src + gr * DDIM + k);
        union { __hip_bfloat162 h; unsigned int u; } p0, p1;
        p0.h = __float22bfloat162_rn(make_float2(v.x, v.y));
        p1.h = __float22bfloat162_rn(make_float2(v.z, v.w));
        uint2 st; st.x = p0.u; st.y = p1.u;
        *(uint2*)(lds + r * LDT + k) = st;
    }
}

// per-row squared norms of the ROUNDED bf16 values; 4 lanes per row
__device__ __forceinline__ void norm64(const unsigned short* __restrict__ tile,
                                       float* __restrict__ nrm, int t) {
    int r = t >> 2, seg = t & 3;
    const unsigned short* p = tile + r * LDT + seg * 32;
    float q = 0.0f;
    #pragma unroll
    for (int j = 0; j < 4; ++j) {
        short8 v = *(const short8*)(p + j * 8);
        #pragma unroll
        for (int e = 0; e < 8; ++e) { float f = bf2f((unsigned short)v[e]); q = fmaf(f, f, q); }
    }
    q += __shfl_xor(q, 1);
    q += __shfl_xor(q, 2);
    if (seg == 0) nrm[r] = q;
}

// 64x64 block tile: 4 waves, each a 2x2 of 16x16x32 bf16 MFMA tiles
__device__ __forceinline__ void gemm64(const unsigned short* __restrict__ As,
                                       const unsigned short* __restrict__ Bs,
                                       int lane, int w, floatx4 acc[2][2]) {
    int wm = (w >> 1) * 32, wn = (w & 1) * 32;
    int lm = lane & 15, q = lane >> 4;
    #pragma unroll
    for (int ks = 0; ks < 4; ++ks) {
        int ko = ks * 32 + q * 8;
        short8 a0 = *(const short8*)(As + (wm + lm) * LDT + ko);
        short8 a1 = *(const short8*)(As + (wm + 16 + lm) * LDT + ko);
        short8 b0 = *(const short8*)(Bs + (wn + lm) * LDT + ko);
        short8 b1 = *(const short8*)(Bs + (wn + 16 + lm) * LDT + ko);
        acc[0][0] = __builtin_amdgcn_mfma_f32_16x16x32_bf16(a0, b0, acc[0][0], 0, 0, 0);
        acc[0][1] = __builtin_amdgcn_mfma_f32_16x16x32_bf16(a0, b1, acc[0][1], 0, 0, 0);
        acc[1][0] = __builtin_amdgcn_mfma_f32_16x16x32_bf16(a1, b0, acc[1][0], 0, 0, 0);
        acc[1][1] = __builtin_amdgcn_mfma_f32_16x16x32_bf16(a1, b1, acc[1][1], 0, 0, 0);
    }
}

// ---- proto: upper-triangle 64x64 tiles of ||w_c1 - w_c2||, partial -> ws[bid] ----
__global__ __launch_bounds__(256) void proto_kernel(const float* __restrict__ W,
                                                    float* __restrict__ ws) {
    int by = blockIdx.y, bx = blockIdx.x, bid = by * 16 + bx;
    if (by > bx) {                       // symmetric half: contribute zero
        if (threadIdx.x == 0) ws[bid] = 0.0f;
        return;
    }
    __shared__ __align__(16) unsigned short As[64 * LDT];
    __shared__ __align__(16) unsigned short Bs[64 * LDT];
    __shared__ float nA[64], nB[64], red[4];
    int t = threadIdx.x;
    int row0 = by * 64, col0 = bx * 64;
    stage_cvt(W, row0, NC - 1, As, t);
    stage_cvt(W, col0, NC - 1, Bs, t);
    __syncthreads();
    norm64(As, nA, t);
    norm64(Bs, nB, t);
    int lane = t & 63, w = t >> 6;
    floatx4 acc[2][2] = {{{0,0,0,0},{0,0,0,0}},{{0,0,0,0},{0,0,0,0}}};
    gemm64(As, Bs, lane, w, acc);
    __syncthreads();                     // norms visible
    int wm = (w >> 1) * 32, wn = (w & 1) * 32;
    int lm = lane & 15, q = lane >> 4;
    float local = 0.0f;
    #pragma unroll
    for (int ti = 0; ti < 2; ++ti)
        #pragma unroll
        for (int tj = 0; tj < 2; ++tj) {
            int lc2 = wn + tj * 16 + lm;
            if (col0 + lc2 < NC) {
                float n2 = nB[lc2];
                #pragma unroll
                for (int r = 0; r < 4; ++r) {
                    int lc1 = wm + ti * 16 + q * 4 + r;
                    if (row0 + lc1 < NC) {
                        float d2 = nA[lc1] + n2 - 2.0f * acc[ti][tj][r];
                        local += sqrtf(fmaxf(d2, 0.0f));
                    }
                }
            }
        }
    if (by != bx) local *= 2.0f;         // symmetric double-count
    #pragma unroll
    for (int off = 32; off > 0; off >>= 1) local += __shfl_down(local, off);
    if (lane == 0) red[w] = local;
    __syncthreads();
    if (t == 0) ws[bid] = red[0] + red[1] + red[2] + red[3];   // plain store
}

// ---- dist: out[b,c] = protoSum - ||f_b - w_c|| ----------------------------------
__global__ __launch_bounds__(256) void dist_kernel(const float* __restrict__ F,
                                                   const float* __restrict__ W,
                                                   const float* __restrict__ ws,
                                                   float* __restrict__ out) {
    __shared__ __align__(16) unsigned short As[64 * LDT];
    __shared__ __align__(16) unsigned short Bs[64 * LDT];
    __shared__ float nA[64], nB[64], red2[4];
    int t = threadIdx.x;
    int row0 = blockIdx.y * 64, col0 = blockIdx.x * 64;

    float pv = ws[t & (NPB - 1)];        // one partial per thread (coalesced 1 KB)
    stage_cvt(F, row0, NB - 1, As, t);
    stage_cvt(W, col0, NC - 1, Bs, t);
    #pragma unroll
    for (int off = 32; off > 0; off >>= 1) pv += __shfl_down(pv, off);
    if ((t & 63) == 0) red2[t >> 6] = pv;
    __syncthreads();                     // staging + red2 both visible
    float proto = red2[0] + red2[1] + red2[2] + red2[3];

    norm64(As, nA, t);
    norm64(Bs, nB, t);
    int lane = t & 63, w = t >> 6;
    floatx4 acc[2][2] = {{{0,0,0,0},{0,0,0,0}},{{0,0,0,0},{0,0,0,0}}};
    gemm64(As, Bs, lane, w, acc);
    __syncthreads();                     // norms visible
    int wm = (w >> 1) * 32, wn = (w & 1) * 32;
    int lm = lane & 15, q = lane >> 4;
    #pragma unroll
    for (int ti = 0; ti < 2; ++ti)
        #pragma unroll
        for (int tj = 0; tj < 2; ++tj) {
            int lc2 = wn + tj * 16 + lm;
            int cg  = col0 + lc2;
            if (cg < NC) {
                float n2 = nB[lc2];
                #pragma unroll
                for (int r = 0; r < 4; ++r) {
                    int mg = row0 + wm + ti * 16 + q * 4 + r;
                    float d2 = nA[wm + ti * 16 + q * 4 + r] + n2 - 2.0f * acc[ti][tj][r];
                    out[mg * NC + cg] = proto - sqrtf(fmaxf(d2, 0.0f));
                }
            }
        }
}

extern "C" void kernel_launch(void* const* d_in, const int* in_sizes, int n_in,
                              void* d_out, int out_size, void* d_ws, size_t ws_size,
                              hipStream_t stream) {
    const float* F  = (const float*)d_in[0];   // (2048,128)
    const float* Wm = (const float*)d_in[1];   // (1000,128)
    float* out = (float*)d_out;                // (2048,1000)
    float* ws  = (float*)d_ws;

    proto_kernel<<<dim3(16, 16), 256, 0, stream>>>(Wm, ws);       // partials -> ws[0..255]
    dist_kernel <<<dim3(16, 32), 256, 0, stream>>>(F, Wm, ws, out);
}